// Round 4
// baseline (404.125 us; speedup 1.0000x reference)
//
#include <hip/hip_runtime.h>
#include <hip/hip_bf16.h>

// Problem constants (from reference)
#define B_SZ   2
#define N_IN   163842
#define N_OUT  40962
#define C_DIM  128
#define K_CAND 7
// 1/(2*SIGMA^2), SIGMA=0.4
#define INV_2SIG2 3.125f

#define SCAN_T 1024
#define NBLK_SCAN ((N_OUT + SCAN_T - 1) / SCAN_T)   // 41
#define GATHER_BLOCKS 2048

typedef float f32x4 __attribute__((ext_vector_type(4)));
typedef unsigned short u16x8 __attribute__((ext_vector_type(8)));

__device__ __forceinline__ float bf2f(unsigned short u) {
    return __uint_as_float((unsigned)u << 16);
}
__device__ __forceinline__ unsigned short f2bf(float f) {
    // RNE, matches __float2bfloat16 for non-NaN inputs
    unsigned u = __float_as_uint(f);
    return (unsigned short)((u + 0x7fffu + ((u >> 16) & 1u)) >> 16);
}

// ---------- Pass A: count children per parent ----------
__global__ __launch_bounds__(256) void count_kernel(
    const int* __restrict__ parent, int* __restrict__ count)
{
    int n = blockIdx.x * 256 + threadIdx.x;
    if (n < N_IN) atomicAdd(&count[parent[n]], 1);
}

// ---------- Pass B1: per-block exclusive scan, COALESCED (1 elem/thread) ----------
__global__ __launch_bounds__(SCAN_T) void scan1_kernel(
    const int* __restrict__ count, int* __restrict__ offs, int* __restrict__ bsum)
{
    __shared__ int wsum[SCAN_T / 64];
    const int t    = threadIdx.x;
    const int lane = t & 63;
    const int wid  = t >> 6;
    const int j    = blockIdx.x * SCAN_T + t;
    const int c = (j < N_OUT) ? count[j] : 0;

    // wave-inclusive scan via shfl
    int v = c;
    #pragma unroll
    for (int off = 1; off < 64; off <<= 1) {
        int u = __shfl_up(v, off, 64);
        if (lane >= off) v += u;
    }
    if (lane == 63) wsum[wid] = v;
    __syncthreads();
    // wave 0 scans the 16 wave totals (inclusive)
    if (wid == 0 && lane < SCAN_T / 64) {
        int w = wsum[lane];
        #pragma unroll
        for (int off = 1; off < SCAN_T / 64; off <<= 1) {
            int u = __shfl_up(w, off, 64);
            if (lane >= off) w += u;
        }
        wsum[lane] = w;
    }
    __syncthreads();
    const int wbase = (wid == 0) ? 0 : wsum[wid - 1];
    if (j < N_OUT) offs[j] = wbase + v - c;                 // exclusive in block
    if (t == 0) bsum[blockIdx.x] = wsum[SCAN_T / 64 - 1];   // block total
}

// ---------- Pass B2: scan the 41 block sums (one wave) ----------
__global__ __launch_bounds__(64) void scan2_kernel(
    const int* __restrict__ bsum, int* __restrict__ bbase)
{
    const int lane = threadIdx.x;
    int s = (lane < NBLK_SCAN) ? bsum[lane] : 0;
    int v = s;
    #pragma unroll
    for (int off = 1; off < 64; off <<= 1) {
        int u = __shfl_up(v, off, 64);
        if (lane >= off) v += u;
    }
    if (lane < NBLK_SCAN) bbase[lane] = v - s;   // exclusive
}

// ---------- Pass B3: add block bases ----------
__global__ __launch_bounds__(SCAN_T) void scan3_kernel(
    int* __restrict__ offs, const int* __restrict__ bbase)
{
    const int j = blockIdx.x * SCAN_T + threadIdx.x;
    if (j < N_OUT && blockIdx.x > 0) offs[j] += bbase[blockIdx.x];
}

// ---------- Pass C: fill permutation (CSR child lists) ----------
// atomicSub on count doubles as the cursor. Also stash omega[n] at the same
// CSR slot so the reduce pass never does the dependent omega[perm[i]] hop.
__global__ __launch_bounds__(256) void fill_kernel(
    const int* __restrict__ parent, const int* __restrict__ offs,
    const float* __restrict__ omega,
    int* __restrict__ count, int* __restrict__ perm,
    float* __restrict__ om_perm)
{
    int n = blockIdx.x * 256 + threadIdx.x;
    if (n < N_IN) {
        const int p = parent[n];
        const float om = omega[n];
        const int pos = offs[p] + atomicSub(&count[p], 1) - 1;
        perm[pos] = n;
        om_perm[pos] = om;
    }
}

// ---------- Pass D: per-parent reduce, normalize, store bf16 ----------
// One 64-lane wave per parent. Lanes 0-31 accumulate batch 0, lanes 32-63
// batch 1 (each lane owns 4 channels). Child ids+omegas loaded coalesced
// then shfl-broadcast; unroll 8 keeps 8 x-row loads in flight (128-VGPR cap
// via launch_bounds min-waves=4 so the compiler doesn't recycle registers).
// down layout: row p = 512B contiguous [half0 c0..127 | half1 c0..127].
__global__ __launch_bounds__(256, 4) void reduce_kernel(
    const float* __restrict__ x,       // (B, N_IN, C)
    const int*   __restrict__ offs,
    const int*   __restrict__ perm,
    const float* __restrict__ om_perm,
    __hip_bfloat16* __restrict__ down) // (N_OUT, B, C) interleaved, normalized
{
    const int wid  = threadIdx.x >> 6;           // wave in block: 0..3
    const int lane = threadIdx.x & 63;
    const int p = blockIdx.x * 4 + wid;
    if (p >= N_OUT) return;

    const int beg = offs[p];
    const int end = (p + 1 < N_OUT) ? offs[p + 1] : N_IN;
    const int cnt = end - beg;

    const int half = lane >> 5;                  // batch index
    const int l    = lane & 31;                  // float4 channel group
    const f32x4* x4 = (const f32x4*)x;
    const size_t bofs = (size_t)half * N_IN * 32;

    f32x4 acc = {0.f, 0.f, 0.f, 0.f};
    float ds = 0.f;

    for (int cbase = 0; cbase < cnt; cbase += 64) {
        const int m = min(64, cnt - cbase);
        int   myn  = 0;
        float myom = 0.f;
        if (lane < m) {
            myn  = perm[beg + cbase + lane];
            myom = om_perm[beg + cbase + lane];
        }
        #pragma unroll 8
        for (int j = 0; j < m; ++j) {
            const int   n  = __shfl(myn,  j);
            const float om = __shfl(myom, j);
            ds += om;
            const f32x4 v = __builtin_nontemporal_load(&x4[bofs + (size_t)n * 32 + l]);
            acc.x = fmaf(v.x, om, acc.x);
            acc.y = fmaf(v.y, om, acc.y);
            acc.z = fmaf(v.z, om, acc.z);
            acc.w = fmaf(v.w, om, acc.w);
        }
    }
    const float inv = 1.f / fmaxf(ds, 1e-8f);

    ushort4 hh;
    hh.x = f2bf(acc.x * inv);
    hh.y = f2bf(acc.y * inv);
    hh.z = f2bf(acc.z * inv);
    hh.w = f2bf(acc.w * inv);
    // row p: 64 ushort4 units; lane covers shorts [lane*4, lane*4+4)
    ((ushort4*)down)[(size_t)p * 64 + lane] = hh;
}

// ---------- Pass E: weighted gather (persistent, pipelined) ----------
// Each 32-lane group owns a pair of rows (n0=2*pi, n0+1); grid-stride over
// pairs. Per candidate row p one contiguous 512B load (both halves).
// Next pair's weights are prefetched while current FMAs drain.
// launch_bounds(256,4): 128-VGPR cap so all 14 down-loads stay in flight.
__global__ __launch_bounds__(256, 4) void gather_kernel(
    const float* __restrict__ delta,     // (N_IN, K)
    const float* __restrict__ cand_mask, // (N_IN, K)
    const int*   __restrict__ cand_idx,  // (N_IN, K)
    const __hip_bfloat16* __restrict__ down, // (N_OUT, B, C) interleaved
    float* __restrict__ out)             // (B, N_IN, C)
{
    const int wid  = threadIdx.x >> 6;   // wave in block 0..3
    const int lane = threadIdx.x & 63;
    const int grp  = lane >> 5;          // 0..1 within wave
    const int l5   = lane & 31;
    const int gid  = (blockIdx.x * 4 + wid) * 2 + grp;   // 32-group id
    const int ngroups = GATHER_BLOCKS * 8;
    const int npairs  = N_IN / 2;        // N_IN is even

    const int sub = l5 >> 3;             // 0..3 ; subs 0,1 carry weights
    const int ls  = l5 & 7;

    const u16x8* d8 = (const u16x8*)down;
    f32x4* o4 = (f32x4*)out;
    const int half = l5 >> 4;            // batch index for my 8 channels
    const int c16  = l5 & 15;            // 8-channel group within half

    // ---- prologue: weights for first pair ----
    float w = 0.f;
    int pidx = 0;
    {
        const int pi = gid;
        if (pi < npairs && sub < 2 && ls < K_CAND) {
            const int n = pi * 2 + sub;
            const float d   = __builtin_nontemporal_load(&delta[(size_t)n * K_CAND + ls]);
            const float msk = __builtin_nontemporal_load(&cand_mask[(size_t)n * K_CAND + ls]);
            pidx = __builtin_nontemporal_load(&cand_idx[(size_t)n * K_CAND + ls]);
            w = __expf(-d * d * INV_2SIG2) * msk;
        }
    }

    for (int pi = gid; pi < npairs; pi += ngroups) {
        // ---- finish weights: sum over 8-lane subgroup (lane 7 holds 0) ----
        float s = w;
        s += __shfl_xor(s, 1, 8);
        s += __shfl_xor(s, 2, 8);
        s += __shfl_xor(s, 4, 8);
        const float coef = w / fmaxf(s, 1e-8f);

        float cf[2][K_CAND];
        int   pk[2][K_CAND];
        #pragma unroll
        for (int r = 0; r < 2; ++r)
            #pragma unroll
            for (int k = 0; k < K_CAND; ++k) {
                cf[r][k] = __shfl(coef, r * 8 + k, 32);
                pk[r][k] = __shfl(pidx, r * 8 + k, 32);
            }

        // ---- issue all 14 row loads (512B contiguous per candidate) ----
        u16x8 v[2][K_CAND];
        #pragma unroll
        for (int r = 0; r < 2; ++r)
            #pragma unroll
            for (int k = 0; k < K_CAND; ++k)
                v[r][k] = d8[(size_t)pk[r][k] * 32 + l5];

        // ---- prefetch next pair's weights while loads are in flight ----
        const int pn = pi + ngroups;
        float w2 = 0.f;
        int pidx2 = 0;
        if (pn < npairs && sub < 2 && ls < K_CAND) {
            const int n = pn * 2 + sub;
            const float d   = __builtin_nontemporal_load(&delta[(size_t)n * K_CAND + ls]);
            const float msk = __builtin_nontemporal_load(&cand_mask[(size_t)n * K_CAND + ls]);
            pidx2 = __builtin_nontemporal_load(&cand_idx[(size_t)n * K_CAND + ls]);
            w2 = __expf(-d * d * INV_2SIG2) * msk;
        }

        // ---- FMA + store ----
        const int n0 = pi * 2;
        #pragma unroll
        for (int r = 0; r < 2; ++r) {
            f32x4 acc0 = {0.f, 0.f, 0.f, 0.f};
            f32x4 acc1 = {0.f, 0.f, 0.f, 0.f};
            #pragma unroll
            for (int k = 0; k < K_CAND; ++k) {
                const float c = cf[r][k];
                acc0.x = fmaf(c, bf2f(v[r][k].s0), acc0.x);
                acc0.y = fmaf(c, bf2f(v[r][k].s1), acc0.y);
                acc0.z = fmaf(c, bf2f(v[r][k].s2), acc0.z);
                acc0.w = fmaf(c, bf2f(v[r][k].s3), acc0.w);
                acc1.x = fmaf(c, bf2f(v[r][k].s4), acc1.x);
                acc1.y = fmaf(c, bf2f(v[r][k].s5), acc1.y);
                acc1.z = fmaf(c, bf2f(v[r][k].s6), acc1.z);
                acc1.w = fmaf(c, bf2f(v[r][k].s7), acc1.w);
            }
            const size_t obase = ((size_t)half * N_IN + n0 + r) * 32 + (size_t)c16 * 2;
            __builtin_nontemporal_store(acc0, &o4[obase]);
            __builtin_nontemporal_store(acc1, &o4[obase + 1]);
        }

        w = w2;
        pidx = pidx2;
    }
}

extern "C" void kernel_launch(void* const* d_in, const int* in_sizes, int n_in,
                              void* d_out, int out_size, void* d_ws, size_t ws_size,
                              hipStream_t stream) {
    const float* x         = (const float*)d_in[0];
    const float* omega     = (const float*)d_in[1];
    const float* delta     = (const float*)d_in[2];
    const float* cand_mask = (const float*)d_in[3];
    const int*   parent    = (const int*)d_in[4];
    const int*   cand_idx  = (const int*)d_in[5];
    float* out = (float*)d_out;

    // workspace: down bf16 | count | offs | perm | om_perm | bsum | bbase
    __hip_bfloat16* down = (__hip_bfloat16*)d_ws;
    int*   count   = (int*)(down + (size_t)B_SZ * N_OUT * C_DIM);
    int*   offs    = count + N_OUT;
    int*   perm    = offs + N_OUT;
    float* om_perm = (float*)(perm + N_IN);
    int*   bsum    = (int*)(om_perm + N_IN);
    int*   bbase   = bsum + NBLK_SCAN;

    // zero count only (164 KB)
    hipMemsetAsync(count, 0, (size_t)N_OUT * sizeof(int), stream);

    const int nblk = (N_IN + 255) / 256;
    count_kernel<<<nblk, 256, 0, stream>>>(parent, count);
    scan1_kernel<<<NBLK_SCAN, SCAN_T, 0, stream>>>(count, offs, bsum);
    scan2_kernel<<<1, 64, 0, stream>>>(bsum, bbase);
    scan3_kernel<<<NBLK_SCAN, SCAN_T, 0, stream>>>(offs, bbase);
    fill_kernel<<<nblk, 256, 0, stream>>>(parent, offs, omega, count, perm, om_perm);
    reduce_kernel<<<(N_OUT + 3) / 4, 256, 0, stream>>>(x, offs, perm, om_perm, down);
    gather_kernel<<<GATHER_BLOCKS, 256, 0, stream>>>(
        delta, cand_mask, cand_idx, down, out);
}

// Round 5
// 396.907 us; speedup vs baseline: 1.0182x; 1.0182x over previous
//
#include <hip/hip_runtime.h>
#include <hip/hip_bf16.h>

// Problem constants (from reference)
#define B_SZ   2
#define N_IN   163842
#define N_OUT  40962
#define C_DIM  128
#define K_CAND 7
// 1/(2*SIGMA^2), SIGMA=0.4
#define INV_2SIG2 3.125f

#define SCAN_T 1024
#define NBLK_SCAN ((N_OUT + SCAN_T - 1) / SCAN_T)   // 41

typedef float f32x4 __attribute__((ext_vector_type(4)));
typedef unsigned short u16x8 __attribute__((ext_vector_type(8)));

__device__ __forceinline__ float bf2f(unsigned short u) {
    return __uint_as_float((unsigned)u << 16);
}
__device__ __forceinline__ unsigned short f2bf(float f) {
    // RNE, matches __float2bfloat16 for non-NaN inputs
    unsigned u = __float_as_uint(f);
    return (unsigned short)((u + 0x7fffu + ((u >> 16) & 1u)) >> 16);
}

// ---------- Pass A: count children per parent ----------
__global__ __launch_bounds__(256) void count_kernel(
    const int* __restrict__ parent, int* __restrict__ count)
{
    int n = blockIdx.x * 256 + threadIdx.x;
    if (n < N_IN) atomicAdd(&count[parent[n]], 1);
}

// ---------- Pass B1: per-block exclusive scan, COALESCED (1 elem/thread) ----------
__global__ __launch_bounds__(SCAN_T) void scan1_kernel(
    const int* __restrict__ count, int* __restrict__ offs, int* __restrict__ bsum)
{
    __shared__ int wsum[SCAN_T / 64];
    const int t    = threadIdx.x;
    const int lane = t & 63;
    const int wid  = t >> 6;
    const int j    = blockIdx.x * SCAN_T + t;
    const int c = (j < N_OUT) ? count[j] : 0;

    // wave-inclusive scan via shfl
    int v = c;
    #pragma unroll
    for (int off = 1; off < 64; off <<= 1) {
        int u = __shfl_up(v, off, 64);
        if (lane >= off) v += u;
    }
    if (lane == 63) wsum[wid] = v;
    __syncthreads();
    // wave 0 scans the 16 wave totals (inclusive)
    if (wid == 0 && lane < SCAN_T / 64) {
        int w = wsum[lane];
        #pragma unroll
        for (int off = 1; off < SCAN_T / 64; off <<= 1) {
            int u = __shfl_up(w, off, 64);
            if (lane >= off) w += u;
        }
        wsum[lane] = w;
    }
    __syncthreads();
    const int wbase = (wid == 0) ? 0 : wsum[wid - 1];
    if (j < N_OUT) offs[j] = wbase + v - c;                 // exclusive in block
    if (t == 0) bsum[blockIdx.x] = wsum[SCAN_T / 64 - 1];   // block total
}

// ---------- Pass B2: scan the 41 block sums (one wave) ----------
__global__ __launch_bounds__(64) void scan2_kernel(
    const int* __restrict__ bsum, int* __restrict__ bbase)
{
    const int lane = threadIdx.x;
    int s = (lane < NBLK_SCAN) ? bsum[lane] : 0;
    int v = s;
    #pragma unroll
    for (int off = 1; off < 64; off <<= 1) {
        int u = __shfl_up(v, off, 64);
        if (lane >= off) v += u;
    }
    if (lane < NBLK_SCAN) bbase[lane] = v - s;   // exclusive
}

// ---------- Pass B3: add block bases ----------
__global__ __launch_bounds__(SCAN_T) void scan3_kernel(
    int* __restrict__ offs, const int* __restrict__ bbase)
{
    const int j = blockIdx.x * SCAN_T + threadIdx.x;
    if (j < N_OUT && blockIdx.x > 0) offs[j] += bbase[blockIdx.x];
}

// ---------- Pass C: fill permutation (CSR child lists) ----------
// atomicSub on count doubles as the cursor. Also stash omega[n] at the same
// CSR slot so the reduce pass never does the dependent omega[perm[i]] hop.
__global__ __launch_bounds__(256) void fill_kernel(
    const int* __restrict__ parent, const int* __restrict__ offs,
    const float* __restrict__ omega,
    int* __restrict__ count, int* __restrict__ perm,
    float* __restrict__ om_perm)
{
    int n = blockIdx.x * 256 + threadIdx.x;
    if (n < N_IN) {
        const int p = parent[n];
        const float om = omega[n];
        const int pos = offs[p] + atomicSub(&count[p], 1) - 1;
        perm[pos] = n;
        om_perm[pos] = om;
    }
}

// ---------- Pass D: per-parent reduce, normalize, store bf16 ----------
// TWO parents per wave: each 32-lane group owns one parent; lane owns 4
// channels of BOTH batch halves (2 f32x4 loads per child). Halves the wave
// count and amortizes the offs->perm->x chain vs 1 parent/wave. Adjacent
// parents' CSR segments are contiguous so the two groups' perm reads form
// one near-contiguous region.
// down layout: row p = 512B contiguous [half0 c0..127 | half1 c0..127].
__global__ __launch_bounds__(256) void reduce_kernel(
    const float* __restrict__ x,       // (B, N_IN, C)
    const int*   __restrict__ offs,
    const int*   __restrict__ perm,
    const float* __restrict__ om_perm,
    __hip_bfloat16* __restrict__ down) // (N_OUT, B, C) interleaved, normalized
{
    const int wid  = threadIdx.x >> 6;           // wave in block: 0..3
    const int lane = threadIdx.x & 63;
    const int grp  = lane >> 5;                  // 0..1 -> parent within wave
    const int l5   = lane & 31;                  // float4 channel group
    const int p = blockIdx.x * 8 + wid * 2 + grp;
    if (p >= N_OUT) return;

    const int beg = offs[p];
    const int end = (p + 1 < N_OUT) ? offs[p + 1] : N_IN;
    const int cnt = end - beg;

    const f32x4* x4 = (const f32x4*)x;

    f32x4 acc0 = {0.f, 0.f, 0.f, 0.f};
    f32x4 acc1 = {0.f, 0.f, 0.f, 0.f};
    float ds = 0.f;

    for (int cbase = 0; cbase < cnt; cbase += 32) {
        const int m = min(32, cnt - cbase);
        int   myn  = 0;
        float myom = 0.f;
        if (l5 < m) {
            myn  = perm[beg + cbase + l5];
            myom = om_perm[beg + cbase + l5];
        }
        #pragma unroll 4
        for (int j = 0; j < m; ++j) {
            const int   n  = __shfl(myn,  j, 32);
            const float om = __shfl(myom, j, 32);
            ds += om;
            const f32x4 v0 = __builtin_nontemporal_load(&x4[(size_t)n * 32 + l5]);
            const f32x4 v1 = __builtin_nontemporal_load(&x4[((size_t)N_IN + n) * 32 + l5]);
            acc0.x = fmaf(v0.x, om, acc0.x);
            acc0.y = fmaf(v0.y, om, acc0.y);
            acc0.z = fmaf(v0.z, om, acc0.z);
            acc0.w = fmaf(v0.w, om, acc0.w);
            acc1.x = fmaf(v1.x, om, acc1.x);
            acc1.y = fmaf(v1.y, om, acc1.y);
            acc1.z = fmaf(v1.z, om, acc1.z);
            acc1.w = fmaf(v1.w, om, acc1.w);
        }
    }
    const float inv = 1.f / fmaxf(ds, 1e-8f);

    ushort4 h0, h1;
    h0.x = f2bf(acc0.x * inv); h0.y = f2bf(acc0.y * inv);
    h0.z = f2bf(acc0.z * inv); h0.w = f2bf(acc0.w * inv);
    h1.x = f2bf(acc1.x * inv); h1.y = f2bf(acc1.y * inv);
    h1.z = f2bf(acc1.z * inv); h1.w = f2bf(acc1.w * inv);
    // row p: 64 ushort4 units = [half0: units 0..31 | half1: units 32..63]
    ((ushort4*)down)[(size_t)p * 64 + l5]      = h0;
    ((ushort4*)down)[(size_t)p * 64 + 32 + l5] = h1;
}

// ---------- Pass E: weighted gather ----------
// One 32-lane group per row n (8 rows per 256-block). Per candidate p one
// CONTIGUOUS 512B load (interleaved down row covers both batch halves).
// Weights in lanes 0..6, summed via shfl_xor, broadcast via shfl.
// Default occupancy (r4 showed deep-MLP + low occupancy is a net loss:
// this pattern is memory-system-bound, occupancy is what feeds the fabric).
__global__ __launch_bounds__(256) void gather_kernel(
    const float* __restrict__ delta,     // (N_IN, K)
    const float* __restrict__ cand_mask, // (N_IN, K)
    const int*   __restrict__ cand_idx,  // (N_IN, K)
    const __hip_bfloat16* __restrict__ down, // (N_OUT, B, C) interleaved
    float* __restrict__ out)             // (B, N_IN, C)
{
    const int wid  = threadIdx.x >> 6;   // wave in block 0..3
    const int lane = threadIdx.x & 63;
    const int grp  = lane >> 5;          // 0..1 within wave
    const int l5   = lane & 31;
    const int n    = blockIdx.x * 8 + wid * 2 + grp;
    if (n >= N_IN) return;               // whole 32-group exits together

    // ---- weights: lanes 0..6 of this group ----
    float w = 0.f;
    int pidx = 0;
    if (l5 < K_CAND) {
        const float d   = __builtin_nontemporal_load(&delta[(size_t)n * K_CAND + l5]);
        const float msk = __builtin_nontemporal_load(&cand_mask[(size_t)n * K_CAND + l5]);
        pidx = __builtin_nontemporal_load(&cand_idx[(size_t)n * K_CAND + l5]);
        w = __expf(-d * d * INV_2SIG2) * msk;
    }
    // sum over 8-lane subgroup (lane 7 holds 0)
    float s = w;
    s += __shfl_xor(s, 1, 8);
    s += __shfl_xor(s, 2, 8);
    s += __shfl_xor(s, 4, 8);
    const float coef = w / fmaxf(s, 1e-8f);

    float cf[K_CAND];
    int   pk[K_CAND];
    #pragma unroll
    for (int k = 0; k < K_CAND; ++k) {
        cf[k] = __shfl(coef, k, 32);
        pk[k] = __shfl(pidx, k, 32);
    }

    // each candidate row = one contiguous 512B segment (both halves);
    // lane l5 covers shorts [l5*8, l5*8+8) of the row.
    const u16x8* d8 = (const u16x8*)down;
    u16x8 v[K_CAND];
    #pragma unroll
    for (int k = 0; k < K_CAND; ++k)
        v[k] = d8[(size_t)pk[k] * 32 + l5];

    f32x4 acc0 = {0.f, 0.f, 0.f, 0.f};
    f32x4 acc1 = {0.f, 0.f, 0.f, 0.f};
    #pragma unroll
    for (int k = 0; k < K_CAND; ++k) {
        const float c = cf[k];
        acc0.x = fmaf(c, bf2f(v[k].s0), acc0.x);
        acc0.y = fmaf(c, bf2f(v[k].s1), acc0.y);
        acc0.z = fmaf(c, bf2f(v[k].s2), acc0.z);
        acc0.w = fmaf(c, bf2f(v[k].s3), acc0.w);
        acc1.x = fmaf(c, bf2f(v[k].s4), acc1.x);
        acc1.y = fmaf(c, bf2f(v[k].s5), acc1.y);
        acc1.z = fmaf(c, bf2f(v[k].s6), acc1.z);
        acc1.w = fmaf(c, bf2f(v[k].s7), acc1.w);
    }
    // my 8 channels live in batch half (l5>>4), channel block (l5&15)
    const int half = l5 >> 4;
    const int c8   = l5 & 15;
    f32x4* o4 = (f32x4*)out;
    const size_t obase = ((size_t)half * N_IN + n) * 32 + (size_t)c8 * 2;
    __builtin_nontemporal_store(acc0, &o4[obase]);
    __builtin_nontemporal_store(acc1, &o4[obase + 1]);
}

extern "C" void kernel_launch(void* const* d_in, const int* in_sizes, int n_in,
                              void* d_out, int out_size, void* d_ws, size_t ws_size,
                              hipStream_t stream) {
    const float* x         = (const float*)d_in[0];
    const float* omega     = (const float*)d_in[1];
    const float* delta     = (const float*)d_in[2];
    const float* cand_mask = (const float*)d_in[3];
    const int*   parent    = (const int*)d_in[4];
    const int*   cand_idx  = (const int*)d_in[5];
    float* out = (float*)d_out;

    // workspace: down bf16 | count | offs | perm | om_perm | bsum | bbase
    __hip_bfloat16* down = (__hip_bfloat16*)d_ws;
    int*   count   = (int*)(down + (size_t)B_SZ * N_OUT * C_DIM);
    int*   offs    = count + N_OUT;
    int*   perm    = offs + N_OUT;
    float* om_perm = (float*)(perm + N_IN);
    int*   bsum    = (int*)(om_perm + N_IN);
    int*   bbase   = bsum + NBLK_SCAN;

    // zero count only (164 KB)
    hipMemsetAsync(count, 0, (size_t)N_OUT * sizeof(int), stream);

    const int nblk = (N_IN + 255) / 256;
    count_kernel<<<nblk, 256, 0, stream>>>(parent, count);
    scan1_kernel<<<NBLK_SCAN, SCAN_T, 0, stream>>>(count, offs, bsum);
    scan2_kernel<<<1, 64, 0, stream>>>(bsum, bbase);
    scan3_kernel<<<NBLK_SCAN, SCAN_T, 0, stream>>>(offs, bbase);
    fill_kernel<<<nblk, 256, 0, stream>>>(parent, offs, omega, count, perm, om_perm);
    reduce_kernel<<<(N_OUT + 7) / 8, 256, 0, stream>>>(x, offs, perm, om_perm, down);
    gather_kernel<<<(N_IN + 7) / 8, 256, 0, stream>>>(
        delta, cand_mask, cand_idx, down, out);
}